// Round 8
// baseline (60.210 us; speedup 1.0000x reference)
//
#include <hip/hip_runtime.h>

#define NE 8              // experts
#define H4 512            // float4 per token row (2048 floats)
#define NTOK 16384        // 4 * 4096 tokens
#define TPW 4             // tokens per wave
#define WPB 8             // waves per block (512 threads)
#define TPB (TPW * WPB)   // 32 tokens per block
#define NBLK (NTOK / TPB) // 512 blocks
#define KC 8              // K-steps
#define C4 64             // float4 per chunk per row (1 KB)
#define NBUF 3            // triple buffer -> prefetch distance 2
#define GATE4 (NE * H4)   // 4096 float4 = 64 KB gate
#define AUX_COEF 0.01f
#define CPOL_NT 2         // GFX940+ CPol NT bit

typedef const __attribute__((address_space(1))) void* gas_ptr;
typedef __attribute__((address_space(3))) void* lds_ptr;

// R7 load/compute structure unchanged (gate in LDS, h triple-buffered via
// global_load_lds + counted vmcnt). NEW TAIL: zero atomics anywhere —
// per-wave butterfly reduction of probs/counts (every token appears in 16
// lanes -> sum/16), per-block partial stored contention-free to
// ws[block*16 + e]; router_aux reduces 512x16 partials. No ws memset needed.
__global__ __launch_bounds__(512)
void router_main(const float* __restrict__ hs, const float* __restrict__ gw,
                 float* __restrict__ out, float* __restrict__ ws)
{
    extern __shared__ float4 smem[];      // [GATE4] gate | [NBUF][TPB][C4] h
    float4* gateL = smem;
    float4* hbuf  = smem + GATE4;

    const int tid = threadIdx.x;
    const float4* __restrict__ hs4 = (const float4*)hs;
    const float4* __restrict__ gw4 = (const float4*)gw;

    // stage gate -> LDS once: 4096 float4 / 512 threads = 8 each
    #pragma unroll
    for (int i = 0; i < GATE4 / 512; ++i)
        gateL[tid + i * 512] = gw4[tid + i * 512];
    __syncthreads();

    const int wave = tid >> 6, lane = tid & 63;
    const int tok0 = blockIdx.x * TPB + wave * TPW;
    const int wrow = wave * TPW;          // this wave's LDS row base

    float acc[TPW][NE];
    #pragma unroll
    for (int r = 0; r < TPW; ++r)
        #pragma unroll
        for (int e = 0; e < NE; ++e) acc[r][e] = 0.f;

    // prologue: stage chunks 0 and 1 (8 ops outstanding)
    #pragma unroll
    for (int k = 0; k < 2; ++k)
        #pragma unroll
        for (int r = 0; r < TPW; ++r)
            __builtin_amdgcn_global_load_lds(
                (gas_ptr)(hs4 + (size_t)(tok0 + r) * H4 + k * C4 + lane),
                (lds_ptr)&hbuf[(k * TPB + wrow + r) * C4], 16, 0, CPOL_NT);

    // kc = 0..5: issue stage(kc+2), vmcnt(8) retires stage(kc), compute kc
    #pragma unroll
    for (int kc = 0; kc < KC - 2; ++kc) {
        const int kn = kc + 2;
        #pragma unroll
        for (int r = 0; r < TPW; ++r)
            __builtin_amdgcn_global_load_lds(
                (gas_ptr)(hs4 + (size_t)(tok0 + r) * H4 + kn * C4 + lane),
                (lds_ptr)&hbuf[((kn % NBUF) * TPB + wrow + r) * C4], 16, 0, CPOL_NT);
        asm volatile("s_waitcnt vmcnt(8)" ::: "memory");
        float4 g[NE];
        #pragma unroll
        for (int e = 0; e < NE; ++e) g[e] = gateL[e * H4 + kc * C4 + lane];
        #pragma unroll
        for (int r = 0; r < TPW; ++r) {
            const float4 h = hbuf[((kc % NBUF) * TPB + wrow + r) * C4 + lane];
            #pragma unroll
            for (int e = 0; e < NE; ++e)
                acc[r][e] += h.x * g[e].x + h.y * g[e].y
                           + h.z * g[e].z + h.w * g[e].w;
        }
    }

    // peeled kc = 6: no new issue; vmcnt(4) retires stage(6)
    asm volatile("s_waitcnt vmcnt(4)" ::: "memory");
    {
        const int kc = KC - 2;
        float4 g[NE];
        #pragma unroll
        for (int e = 0; e < NE; ++e) g[e] = gateL[e * H4 + kc * C4 + lane];
        #pragma unroll
        for (int r = 0; r < TPW; ++r) {
            const float4 h = hbuf[((kc % NBUF) * TPB + wrow + r) * C4 + lane];
            #pragma unroll
            for (int e = 0; e < NE; ++e)
                acc[r][e] += h.x * g[e].x + h.y * g[e].y
                           + h.z * g[e].z + h.w * g[e].w;
        }
    }

    // peeled kc = 7: full drain
    asm volatile("s_waitcnt vmcnt(0)" ::: "memory");
    {
        const int kc = KC - 1;
        float4 g[NE];
        #pragma unroll
        for (int e = 0; e < NE; ++e) g[e] = gateL[e * H4 + kc * C4 + lane];
        #pragma unroll
        for (int r = 0; r < TPW; ++r) {
            const float4 h = hbuf[((kc % NBUF) * TPB + wrow + r) * C4 + lane];
            #pragma unroll
            for (int e = 0; e < NE; ++e)
                acc[r][e] += h.x * g[e].x + h.y * g[e].y
                           + h.z * g[e].z + h.w * g[e].w;
        }
    }

    // full-wave butterfly: every lane ends with complete dots for all 4 tokens
    #pragma unroll
    for (int r = 0; r < TPW; ++r) {
        #pragma unroll
        for (int e = 0; e < NE; ++e) {
            float v = acc[r][e];
            #pragma unroll
            for (int s = 32; s > 0; s >>= 1) v += __shfl_xor(v, s, 64);
            acc[r][e] = v;
        }
    }

    // lane (mod 4) picks its token — static indexing only
    const int ls = lane & 3;
    float lg[NE];
    #pragma unroll
    for (int e = 0; e < NE; ++e)
        lg[e] = (ls == 0) ? acc[0][e] : (ls == 1) ? acc[1][e]
              : (ls == 2) ? acc[2][e] : acc[3][e];

    float m = lg[0];
    #pragma unroll
    for (int e = 1; e < NE; ++e) m = fmaxf(m, lg[e]);
    float p[NE];
    float s = 0.f;
    #pragma unroll
    for (int e = 0; e < NE; ++e) { p[e] = __expf(lg[e] - m); s += p[e]; }
    const float inv = 1.f / s;

    // top-2 on probs; strict '>' keeps lowest index on ties (lax.top_k order)
    float v0 = -1.f; int i0 = 0;
    #pragma unroll
    for (int e = 0; e < NE; ++e) { if (p[e] > v0) { v0 = p[e]; i0 = e; } }
    float v1 = -1.f; int i1 = 0;
    #pragma unroll
    for (int e = 0; e < NE; ++e) { if (e != i0 && p[e] > v1) { v1 = p[e]; i1 = e; } }

    if (lane < TPW) {
        const int tok = tok0 + ls;
        const float wsum = v0 + v1;
        out[tok * 2 + 0] = v0 / wsum;
        out[tok * 2 + 1] = v1 / wsum;
        out[2 * NTOK + tok * 2 + 0] = (float)i0;
        out[2 * NTOK + tok * 2 + 1] = (float)i1;
    }

    // ---- atomic-free aux tail ----
    // all 64 lanes hold their token's probs; each token appears in 16 lanes
    float q[NE], c[NE];
    #pragma unroll
    for (int e = 0; e < NE; ++e) {
        q[e] = p[e] * inv;
        c[e] = ((i0 == e) ? 1.f : 0.f) + ((i1 == e) ? 1.f : 0.f);
    }
    #pragma unroll
    for (int e = 0; e < NE; ++e) {
        #pragma unroll
        for (int sh = 32; sh > 0; sh >>= 1) {
            q[e] += __shfl_xor(q[e], sh, 64);
            c[e] += __shfl_xor(c[e], sh, 64);
        }
    }
    __syncthreads();                       // gate reads done -> reuse its LDS
    float* auxL = (float*)smem;            // [WPB][2*NE]
    if (lane == 0) {
        #pragma unroll
        for (int e = 0; e < NE; ++e) {
            auxL[wave * 2 * NE + e]      = q[e] * 0.0625f;   // /16
            auxL[wave * 2 * NE + NE + e] = c[e] * 0.0625f;
        }
    }
    __syncthreads();
    if (tid < 2 * NE) {
        float sum = 0.f;
        #pragma unroll
        for (int w = 0; w < WPB; ++w) sum += auxL[w * 2 * NE + tid];
        ws[blockIdx.x * 2 * NE + tid] = sum;   // contention-free store
    }
}

// Parallel reduce of 512 x 16 per-block partials, then the aux formula.
__global__ __launch_bounds__(256)
void router_aux(const float* __restrict__ ws, float* __restrict__ out)
{
    __shared__ float red[16][16];
    __shared__ float tot[16];
    const int tid = threadIdx.x;
    const int e = tid & 15, chunk = tid >> 4;
    float s = 0.f;
    for (int k = chunk; k < NBLK; k += 16) s += ws[k * 16 + e];
    red[chunk][e] = s;
    __syncthreads();
    if (tid < 16) {
        float t = 0.f;
        #pragma unroll
        for (int c2 = 0; c2 < 16; ++c2) t += red[c2][tid];
        tot[tid] = t;
    }
    __syncthreads();
    if (tid == 0) {
        float s2 = 0.f;
        #pragma unroll
        for (int e2 = 0; e2 < NE; ++e2) {
            const float ef = tot[NE + e2] / (float)(NTOK * 2);  // expert_frac
            const float rf = tot[e2] / (float)NTOK;             // router_frac
            s2 += ef * rf;
        }
        out[4 * NTOK] = (float)NE * s2 * AUX_COEF;
    }
}

extern "C" void kernel_launch(void* const* d_in, const int* in_sizes, int n_in,
                              void* d_out, int out_size, void* d_ws, size_t ws_size,
                              hipStream_t stream)
{
    const float* hs = (const float*)d_in[0];   // [4,4096,2048] f32
    const float* gw = (const float*)d_in[1];   // [8,2048] f32
    float* out = (float*)d_out;                // 32768 rw | 32768 idx | 1 aux
    float* ws  = (float*)d_ws;                 // 512*16 per-block partials

    const size_t lds_bytes = (GATE4 + NBUF * TPB * C4) * sizeof(float4); // 160 KB
    hipLaunchKernelGGL(router_main, dim3(NBLK), dim3(512), lds_bytes,
                       stream, hs, gw, out, ws);
    hipLaunchKernelGGL(router_aux, dim3(1), dim3(256), 0, stream, ws, out);
}

// Round 10
// 45.647 us; speedup vs baseline: 1.3190x; 1.3190x over previous
//
#include <hip/hip_runtime.h>

#define NE 8               // experts
#define H4 512             // float4 per token row (2048 floats)
#define NTOK 16384         // 4 * 4096 tokens
#define QK 4               // K-split factor (4 quarters of 512 cols)
#define ITQ 2              // 64-col it-steps per quarter (8 / QK)
#define TPW 4              // tokens per wave
#define TPB 16             // tokens per block (4 waves)
#define NBLK_B 64          // finish-kernel blocks (16384 / 256)
#define AUX_COEF 0.01f

// ws layout (floats): part[QK][NTOK][NE] = 524288 | ws2[NBLK_B*16]
#define WS2_OFF (QK * NTOK * NE)

// clang ext_vector float4 (layout-identical to HIP float4) — the type
// __builtin_nontemporal_load accepts
typedef float f4v __attribute__((ext_vector_type(4)));

// 8-leaf static-index select (rule #20: no runtime array indexing)
#define SEL8(A) ((e2 & 4) ? ((e2 & 2) ? ((e2 & 1) ? A[7] : A[6])   \
                                      : ((e2 & 1) ? A[5] : A[4]))  \
                          : ((e2 & 2) ? ((e2 & 1) ? A[3] : A[2])   \
                                      : ((e2 & 1) ? A[1] : A[0])))

// Kernel A (hot): pure-streaming partial GEMV. One block = 16 tokens x one
// K-quarter. No LDS, no barriers, no waitcnt choreography — maximal
// independent load streams (m13-copy shape). Partial logits -> ws.
__global__ __launch_bounds__(256, 4)
void router_partial(const float* __restrict__ hs, const float* __restrict__ gw,
                    float* __restrict__ part)
{
    const int tid  = threadIdx.x;
    const int wave = tid >> 6, lane = tid & 63;
    const int q    = blockIdx.x & (QK - 1);
    const int tg   = blockIdx.x >> 2;
    const int tok0 = tg * TPB + wave * TPW;      // this wave's first token

    const f4v* __restrict__ hs4 = (const f4v*)hs;
    const f4v* __restrict__ gw4 = (const f4v*)gw;

    float acc[TPW][NE];
    #pragma unroll
    for (int r = 0; r < TPW; ++r)
        #pragma unroll
        for (int e = 0; e < NE; ++e) acc[r][e] = 0.f;

    #pragma unroll
    for (int it = 0; it < ITQ; ++it) {
        const int col = q * (H4 / QK) + it * 64 + lane;
        f4v h[TPW];
        #pragma unroll
        for (int r = 0; r < TPW; ++r)
            h[r] = __builtin_nontemporal_load(
                       &hs4[(size_t)(tok0 + r) * H4 + col]);
        f4v g[NE];
        #pragma unroll
        for (int e = 0; e < NE; ++e) g[e] = gw4[e * H4 + col];
        #pragma unroll
        for (int r = 0; r < TPW; ++r)
            #pragma unroll
            for (int e = 0; e < NE; ++e)
                acc[r][e] += h[r].x * g[e].x + h[r].y * g[e].y
                           + h[r].z * g[e].z + h[r].w * g[e].w;
    }

    // butterfly: every lane gets the full quarter-dot for all 32 (r,e)
    #pragma unroll
    for (int r = 0; r < TPW; ++r)
        #pragma unroll
        for (int e = 0; e < NE; ++e) {
            float v = acc[r][e];
            #pragma unroll
            for (int s = 32; s > 0; s >>= 1) v += __shfl_xor(v, s, 64);
            acc[r][e] = v;
        }

    // lanes 0..31 store one partial each -> one coalesced 128B store/wave
    const int r2 = (lane >> 3) & 3, e2 = lane & 7;
    const float v = (r2 & 2) ? ((r2 & 1) ? SEL8(acc[3]) : SEL8(acc[2]))
                             : ((r2 & 1) ? SEL8(acc[1]) : SEL8(acc[0]));
    if (lane < 32)
        part[((size_t)q * NTOK + tok0 + r2) * NE + e2] = v;
}

// Kernel B: one thread per token. Sum 4 quarter-partials (fixed order),
// softmax + top-2 + renorm, coalesced float2 outputs, per-block aux partial.
__global__ __launch_bounds__(256)
void router_finish(const float* __restrict__ part, float* __restrict__ out,
                   float* __restrict__ ws2)
{
    __shared__ float red[4][2 * NE];
    const int tid = threadIdx.x;
    const int t   = blockIdx.x * 256 + tid;      // token
    const float4* __restrict__ p4 = (const float4*)part;

    float lg[NE];
    {
        float4 a = p4[(size_t)t * 2],  b = p4[(size_t)t * 2 + 1];
        lg[0]=a.x; lg[1]=a.y; lg[2]=a.z; lg[3]=a.w;
        lg[4]=b.x; lg[5]=b.y; lg[6]=b.z; lg[7]=b.w;
    }
    #pragma unroll
    for (int q = 1; q < QK; ++q) {
        float4 a = p4[((size_t)q * NTOK + t) * 2];
        float4 b = p4[((size_t)q * NTOK + t) * 2 + 1];
        lg[0]+=a.x; lg[1]+=a.y; lg[2]+=a.z; lg[3]+=a.w;
        lg[4]+=b.x; lg[5]+=b.y; lg[6]+=b.z; lg[7]+=b.w;
    }

    float m = lg[0];
    #pragma unroll
    for (int e = 1; e < NE; ++e) m = fmaxf(m, lg[e]);
    float p[NE];
    float s = 0.f;
    #pragma unroll
    for (int e = 0; e < NE; ++e) { p[e] = __expf(lg[e] - m); s += p[e]; }
    const float inv = 1.f / s;

    // top-2 on probs; strict '>' keeps lowest index on ties (lax.top_k order)
    float v0 = -1.f; int i0 = 0;
    #pragma unroll
    for (int e = 0; e < NE; ++e) { if (p[e] > v0) { v0 = p[e]; i0 = e; } }
    float v1 = -1.f; int i1 = 0;
    #pragma unroll
    for (int e = 0; e < NE; ++e) { if (e != i0 && p[e] > v1) { v1 = p[e]; i1 = e; } }

    float2* __restrict__ o2 = (float2*)out;
    const float wsum = v0 + v1;
    o2[t]        = make_float2(v0 / wsum, v1 / wsum);
    o2[NTOK + t] = make_float2((float)i0, (float)i1);

    // aux partials: every thread owns exactly one token
    float qv[NE], c[NE];
    #pragma unroll
    for (int e = 0; e < NE; ++e) {
        qv[e] = p[e] * inv;
        c[e]  = ((i0 == e) ? 1.f : 0.f) + ((i1 == e) ? 1.f : 0.f);
    }
    #pragma unroll
    for (int e = 0; e < NE; ++e) {
        #pragma unroll
        for (int sh = 32; sh > 0; sh >>= 1) {
            qv[e] += __shfl_xor(qv[e], sh, 64);
            c[e]  += __shfl_xor(c[e],  sh, 64);
        }
    }
    const int wave = tid >> 6, lane = tid & 63;
    if (lane == 0) {
        #pragma unroll
        for (int e = 0; e < NE; ++e) {
            red[wave][e]      = qv[e];
            red[wave][NE + e] = c[e];
        }
    }
    __syncthreads();
    if (tid < 2 * NE) {
        float sum = red[0][tid] + red[1][tid] + red[2][tid] + red[3][tid];
        ws2[blockIdx.x * 2 * NE + tid] = sum;
    }
}

// Kernel C: reduce 64 x 16 partials -> aux scalar
__global__ __launch_bounds__(128)
void router_aux2(const float* __restrict__ ws2, float* __restrict__ out)
{
    __shared__ float red[8][16];
    __shared__ float tot[16];
    const int tid = threadIdx.x;
    const int e = tid & 15, row = tid >> 4;      // 8 rows x 16
    float s = 0.f;
    #pragma unroll
    for (int k = 0; k < NBLK_B / 8; ++k)
        s += ws2[(row * (NBLK_B / 8) + k) * 16 + e];
    red[row][e] = s;
    __syncthreads();
    if (tid < 16) {
        float t2 = 0.f;
        #pragma unroll
        for (int r = 0; r < 8; ++r) t2 += red[r][tid];
        tot[tid] = t2;
    }
    __syncthreads();
    if (tid == 0) {
        float s2 = 0.f;
        #pragma unroll
        for (int e2 = 0; e2 < NE; ++e2) {
            const float ef = tot[NE + e2] / (float)(NTOK * 2);  // expert_frac
            const float rf = tot[e2] / (float)NTOK;             // router_frac
            s2 += ef * rf;
        }
        out[4 * NTOK] = (float)NE * s2 * AUX_COEF;
    }
}

extern "C" void kernel_launch(void* const* d_in, const int* in_sizes, int n_in,
                              void* d_out, int out_size, void* d_ws, size_t ws_size,
                              hipStream_t stream)
{
    const float* hs = (const float*)d_in[0];   // [4,4096,2048] f32
    const float* gw = (const float*)d_in[1];   // [8,2048] f32
    float* out  = (float*)d_out;               // 32768 rw | 32768 idx | 1 aux
    float* part = (float*)d_ws;                // [4][16384][8] partial logits
    float* ws2  = (float*)d_ws + WS2_OFF;      // [64][16] aux partials

    hipLaunchKernelGGL(router_partial, dim3(NTOK / TPB * QK), dim3(256), 0,
                       stream, hs, gw, part);
    hipLaunchKernelGGL(router_finish, dim3(NBLK_B), dim3(256), 0,
                       stream, part, out, ws2);
    hipLaunchKernelGGL(router_aux2, dim3(1), dim3(128), 0, stream, ws2, out);
}

// Round 11
// 43.779 us; speedup vs baseline: 1.3753x; 1.0427x over previous
//
#include <hip/hip_runtime.h>

#define NE 8               // experts
#define H4 512             // float4 per token row (2048 floats)
#define NTOK 16384         // 4 * 4096 tokens
#define QK 2               // K-split factor (2 halves of 1024 cols)
#define ITQ (8 / QK)       // 64-col it-steps per half = 4
#define TPW 4              // tokens per wave
#define TPB 16             // tokens per block (4 waves)
#define NBLK_B 64          // finish-kernel blocks (16384 / 256)
#define AUX_COEF 0.01f

// ws layout (floats): part[QK][NTOK][NE] | ws2[NBLK_B*16]
#define WS2_OFF (QK * NTOK * NE)

typedef float f4v __attribute__((ext_vector_type(4)));

// 8-leaf static-index select (rule #20: no runtime array indexing)
#define SEL8(A) ((e2 & 4) ? ((e2 & 2) ? ((e2 & 1) ? A[7] : A[6])   \
                                      : ((e2 & 1) ? A[5] : A[4]))  \
                          : ((e2 & 2) ? ((e2 & 1) ? A[3] : A[2])   \
                                      : ((e2 & 1) ? A[1] : A[0])))

// Kernel A (hot): streaming partial GEMV. One block = 16 tokens x one
// K-half (1024 cols). No LDS, no barriers, no NT (input is L3-resident
// across replays -> let the Infinity Cache serve it). Partial logits -> ws.
__global__ __launch_bounds__(256, 4)
void router_partial(const float* __restrict__ hs, const float* __restrict__ gw,
                    float* __restrict__ part)
{
    const int tid  = threadIdx.x;
    const int wave = tid >> 6, lane = tid & 63;
    const int q    = blockIdx.x & (QK - 1);
    const int tg   = blockIdx.x >> 1;            // log2(QK)
    const int tok0 = tg * TPB + wave * TPW;      // this wave's first token

    const f4v* __restrict__ hs4 = (const f4v*)hs;
    const f4v* __restrict__ gw4 = (const f4v*)gw;

    float acc[TPW][NE];
    #pragma unroll
    for (int r = 0; r < TPW; ++r)
        #pragma unroll
        for (int e = 0; e < NE; ++e) acc[r][e] = 0.f;

    #pragma unroll
    for (int it = 0; it < ITQ; ++it) {
        const int col = q * (H4 / QK) + it * 64 + lane;
        f4v h[TPW];
        #pragma unroll
        for (int r = 0; r < TPW; ++r)
            h[r] = hs4[(size_t)(tok0 + r) * H4 + col];
        f4v g[NE];
        #pragma unroll
        for (int e = 0; e < NE; ++e) g[e] = gw4[e * H4 + col];
        #pragma unroll
        for (int r = 0; r < TPW; ++r)
            #pragma unroll
            for (int e = 0; e < NE; ++e)
                acc[r][e] += h[r].x * g[e].x + h[r].y * g[e].y
                           + h[r].z * g[e].z + h[r].w * g[e].w;
    }

    // butterfly: every lane gets the full half-dot for all 32 (r,e)
    #pragma unroll
    for (int r = 0; r < TPW; ++r)
        #pragma unroll
        for (int e = 0; e < NE; ++e) {
            float v = acc[r][e];
            #pragma unroll
            for (int s = 32; s > 0; s >>= 1) v += __shfl_xor(v, s, 64);
            acc[r][e] = v;
        }

    // lanes 0..31 store one partial each -> one coalesced 128B store/wave
    const int r2 = (lane >> 3) & 3, e2 = lane & 7;
    const float v = (r2 & 2) ? ((r2 & 1) ? SEL8(acc[3]) : SEL8(acc[2]))
                             : ((r2 & 1) ? SEL8(acc[1]) : SEL8(acc[0]));
    if (lane < 32)
        part[((size_t)q * NTOK + tok0 + r2) * NE + e2] = v;
}

// Kernel B: one thread per token. Sum QK partials (fixed order),
// softmax + top-2 + renorm, coalesced float2 outputs, per-block aux partial.
__global__ __launch_bounds__(256)
void router_finish(const float* __restrict__ part, float* __restrict__ out,
                   float* __restrict__ ws2)
{
    __shared__ float red[4][2 * NE];
    const int tid = threadIdx.x;
    const int t   = blockIdx.x * 256 + tid;      // token
    const float4* __restrict__ p4 = (const float4*)part;

    float lg[NE];
    {
        float4 a = p4[(size_t)t * 2],  b = p4[(size_t)t * 2 + 1];
        lg[0]=a.x; lg[1]=a.y; lg[2]=a.z; lg[3]=a.w;
        lg[4]=b.x; lg[5]=b.y; lg[6]=b.z; lg[7]=b.w;
    }
    #pragma unroll
    for (int q = 1; q < QK; ++q) {
        float4 a = p4[((size_t)q * NTOK + t) * 2];
        float4 b = p4[((size_t)q * NTOK + t) * 2 + 1];
        lg[0]+=a.x; lg[1]+=a.y; lg[2]+=a.z; lg[3]+=a.w;
        lg[4]+=b.x; lg[5]+=b.y; lg[6]+=b.z; lg[7]+=b.w;
    }

    float m = lg[0];
    #pragma unroll
    for (int e = 1; e < NE; ++e) m = fmaxf(m, lg[e]);
    float p[NE];
    float s = 0.f;
    #pragma unroll
    for (int e = 0; e < NE; ++e) { p[e] = __expf(lg[e] - m); s += p[e]; }
    const float inv = 1.f / s;

    // top-2 on probs; strict '>' keeps lowest index on ties (lax.top_k order)
    float v0 = -1.f; int i0 = 0;
    #pragma unroll
    for (int e = 0; e < NE; ++e) { if (p[e] > v0) { v0 = p[e]; i0 = e; } }
    float v1 = -1.f; int i1 = 0;
    #pragma unroll
    for (int e = 0; e < NE; ++e) { if (e != i0 && p[e] > v1) { v1 = p[e]; i1 = e; } }

    float2* __restrict__ o2 = (float2*)out;
    const float wsum = v0 + v1;
    o2[t]        = make_float2(v0 / wsum, v1 / wsum);
    o2[NTOK + t] = make_float2((float)i0, (float)i1);

    // aux partials: every thread owns exactly one token
    float qv[NE], c[NE];
    #pragma unroll
    for (int e = 0; e < NE; ++e) {
        qv[e] = p[e] * inv;
        c[e]  = ((i0 == e) ? 1.f : 0.f) + ((i1 == e) ? 1.f : 0.f);
    }
    #pragma unroll
    for (int e = 0; e < NE; ++e) {
        #pragma unroll
        for (int sh = 32; sh > 0; sh >>= 1) {
            qv[e] += __shfl_xor(qv[e], sh, 64);
            c[e]  += __shfl_xor(c[e],  sh, 64);
        }
    }
    const int wave = tid >> 6, lane = tid & 63;
    if (lane == 0) {
        #pragma unroll
        for (int e = 0; e < NE; ++e) {
            red[wave][e]      = qv[e];
            red[wave][NE + e] = c[e];
        }
    }
    __syncthreads();
    if (tid < 2 * NE) {
        float sum = red[0][tid] + red[1][tid] + red[2][tid] + red[3][tid];
        ws2[blockIdx.x * 2 * NE + tid] = sum;
    }
}

// Kernel C: reduce 64 x 16 partials -> aux scalar
__global__ __launch_bounds__(128)
void router_aux2(const float* __restrict__ ws2, float* __restrict__ out)
{
    __shared__ float red[8][16];
    __shared__ float tot[16];
    const int tid = threadIdx.x;
    const int e = tid & 15, row = tid >> 4;      // 8 rows x 16
    float s = 0.f;
    #pragma unroll
    for (int k = 0; k < NBLK_B / 8; ++k)
        s += ws2[(row * (NBLK_B / 8) + k) * 16 + e];
    red[row][e] = s;
    __syncthreads();
    if (tid < 16) {
        float t2 = 0.f;
        #pragma unroll
        for (int r = 0; r < 8; ++r) t2 += red[r][tid];
        tot[tid] = t2;
    }
    __syncthreads();
    if (tid == 0) {
        float s2 = 0.f;
        #pragma unroll
        for (int e2 = 0; e2 < NE; ++e2) {
            const float ef = tot[NE + e2] / (float)(NTOK * 2);  // expert_frac
            const float rf = tot[e2] / (float)NTOK;             // router_frac
            s2 += ef * rf;
        }
        out[4 * NTOK] = (float)NE * s2 * AUX_COEF;
    }
}

extern "C" void kernel_launch(void* const* d_in, const int* in_sizes, int n_in,
                              void* d_out, int out_size, void* d_ws, size_t ws_size,
                              hipStream_t stream)
{
    const float* hs = (const float*)d_in[0];   // [4,4096,2048] f32
    const float* gw = (const float*)d_in[1];   // [8,2048] f32
    float* out  = (float*)d_out;               // 32768 rw | 32768 idx | 1 aux
    float* part = (float*)d_ws;                // [QK][16384][8] partial logits
    float* ws2  = (float*)d_ws + WS2_OFF;      // [64][16] aux partials

    hipLaunchKernelGGL(router_partial, dim3(NTOK / TPB * QK), dim3(256), 0,
                       stream, hs, gw, part);
    hipLaunchKernelGGL(router_finish, dim3(NBLK_B), dim3(256), 0,
                       stream, part, out, ws2);
    hipLaunchKernelGGL(router_aux2, dim3(1), dim3(128), 0, stream, ws2, out);
}